// Round 1
// baseline (562.441 us; speedup 1.0000x reference)
//
#include <hip/hip_runtime.h>
#include <stdint.h>
#include <math.h>

// Problem: B=4, S=2048, E=1024, H=16, D=64
// d_in order (setup_inputs dict): x, Wk, Wq, Wv, Wu, bu   (note Wk before Wq!)

typedef __attribute__((ext_vector_type(8))) short bf16x8;
typedef __attribute__((ext_vector_type(4))) float f32x4;

__device__ __forceinline__ short f2bf(float f) {
  union { float f; uint32_t u; } v; v.f = f;
  uint32_t r = v.u + 0x7FFFu + ((v.u >> 16) & 1u);  // RNE
  return (short)(r >> 16);
}

// ---------------- cast fp32 -> bf16, vectorized (G13) ----------------
__global__ __launch_bounds__(256) void cast_kernel(const float* __restrict__ src,
                                                   short* __restrict__ dst, int n) {
  int i = (blockIdx.x * 256 + threadIdx.x) * 8;
  if (i >= n) return;
  const float4* s = (const float4*)(src + i);
  float4 f0 = s[0], f1 = s[1];
  bf16x8 o;
  o[0] = f2bf(f0.x); o[1] = f2bf(f0.y); o[2] = f2bf(f0.z); o[3] = f2bf(f0.w);
  o[4] = f2bf(f1.x); o[5] = f2bf(f1.y); o[6] = f2bf(f1.z); o[7] = f2bf(f1.w);
  *(bf16x8*)(dst + i) = o;
}

// ---------------- B^T GEMM: C[i,j] = sum_k A[i,k]*B[j,k] ----------------
// A: [M][1024] bf16 row-major, B: [1024-rows][1024] bf16 row-major (weights).
// 128x128 tile, 4 waves (2x2), BK=64, XOR-swizzled LDS (T2 pattern).
template <bool F32OUT>
__device__ __forceinline__ void gemm_bt_core(const short* __restrict__ A,
                                             const short* __restrict__ Bm,
                                             short* __restrict__ Cb,
                                             float* __restrict__ Cf,
                                             const float* __restrict__ bias) {
  __shared__ short a_lds[128 * 64];
  __shared__ short b_lds[128 * 64];
  const int tid = threadIdx.x;
  const int w = tid >> 6, l = tid & 63;
  const int l15 = l & 15, lhi = l >> 4;
  const int wr = w >> 1, wc = w & 1;
  const int row0 = blockIdx.x * 128;
  const int col0 = blockIdx.y * 128;

  f32x4 acc[4][4];
#pragma unroll
  for (int m = 0; m < 4; ++m)
#pragma unroll
    for (int n = 0; n < 4; ++n)
      acc[m][n] = (f32x4){0.f, 0.f, 0.f, 0.f};

  for (int kt = 0; kt < 16; ++kt) {
#pragma unroll
    for (int i = 0; i < 4; ++i) {
      int o = i * 4096 + tid * 16;  // linear byte offset in [128][64]x2B tile
      int r = o >> 7;
      int cs = o & 127;
      bf16x8 va = *(const bf16x8*)((const char*)A + (size_t)(row0 + r) * 2048 + kt * 128 + cs);
      bf16x8 vb = *(const bf16x8*)((const char*)Bm + (size_t)(col0 + r) * 2048 + kt * 128 + cs);
      int sw = cs ^ ((r & 7) << 4);
      *(bf16x8*)((char*)a_lds + r * 128 + sw) = va;
      *(bf16x8*)((char*)b_lds + r * 128 + sw) = vb;
    }
    __syncthreads();
#pragma unroll
    for (int kk = 0; kk < 2; ++kk) {
      bf16x8 af[4], bg[4];
#pragma unroll
      for (int m = 0; m < 4; ++m) {
        int r = wr * 64 + m * 16 + l15;
        int cb = (kk * 64 + lhi * 16) ^ ((r & 7) << 4);
        af[m] = *(const bf16x8*)((const char*)a_lds + r * 128 + cb);
      }
#pragma unroll
      for (int n = 0; n < 4; ++n) {
        int r = wc * 64 + n * 16 + l15;
        int cb = (kk * 64 + lhi * 16) ^ ((r & 7) << 4);
        bg[n] = *(const bf16x8*)((const char*)b_lds + r * 128 + cb);
      }
#pragma unroll
      for (int m = 0; m < 4; ++m)
#pragma unroll
        for (int n = 0; n < 4; ++n)
          acc[m][n] = __builtin_amdgcn_mfma_f32_16x16x32_bf16(af[m], bg[n], acc[m][n], 0, 0, 0);
    }
    __syncthreads();
  }

#pragma unroll
  for (int m = 0; m < 4; ++m) {
#pragma unroll
    for (int n = 0; n < 4; ++n) {
      int colg = col0 + wc * 64 + n * 16 + l15;
#pragma unroll
      for (int r = 0; r < 4; ++r) {
        int rowg = row0 + wr * 64 + m * 16 + lhi * 4 + r;
        float v = acc[m][n][r];
        if constexpr (F32OUT) {
          Cf[(size_t)rowg * 1024 + colg] = v + bias[colg];
        } else {
          Cb[(size_t)rowg * 1024 + colg] = f2bf(v);
        }
      }
    }
  }
}

__global__ __launch_bounds__(256) void gemm_qkv_kernel(const short* __restrict__ xb,
                                                       const short* __restrict__ wq,
                                                       const short* __restrict__ wk,
                                                       const short* __restrict__ wv,
                                                       short* qo, short* ko, short* vo) {
  const short* Bm = (blockIdx.z == 0) ? wq : (blockIdx.z == 1) ? wk : wv;
  short* C = (blockIdx.z == 0) ? qo : (blockIdx.z == 1) ? ko : vo;
  gemm_bt_core<false>(xb, Bm, C, nullptr, nullptr);
}

__global__ __launch_bounds__(256) void gemm_out_kernel(const short* __restrict__ ob,
                                                       const short* __restrict__ wu,
                                                       const float* __restrict__ bias,
                                                       float* __restrict__ out) {
  gemm_bt_core<true>(ob, wu, nullptr, out, bias);
}

// ---------------- V transpose: v[b,s,h,d] -> vt[(b*16+h)*64+d][s] ----------------
__global__ __launch_bounds__(256) void transpose_v_kernel(const short* __restrict__ vb,
                                                          short* __restrict__ vt) {
  int st = blockIdx.x, bh = blockIdx.y;
  int b = bh >> 4, h = bh & 15;
  __shared__ short tile[64][66];
  int tid = threadIdx.x;
  int sl = tid >> 2;
  int d0 = (tid & 3) * 16;
  const short* src = vb + (size_t)(b * 2048 + st * 64 + sl) * 1024 + h * 64 + d0;
  bf16x8 v0 = *(const bf16x8*)(src);
  bf16x8 v1 = *(const bf16x8*)(src + 8);
#pragma unroll
  for (int i = 0; i < 8; ++i) tile[d0 + i][sl] = v0[i];
#pragma unroll
  for (int i = 0; i < 8; ++i) tile[d0 + 8 + i][sl] = v1[i];
  __syncthreads();
  int d = tid >> 2;
  int s0 = (tid & 3) * 16;
  bf16x8 o0, o1;
#pragma unroll
  for (int i = 0; i < 8; ++i) o0[i] = tile[d][s0 + i];
#pragma unroll
  for (int i = 0; i < 8; ++i) o1[i] = tile[d][s0 + 8 + i];
  short* dst = vt + (size_t)(bh * 64 + d) * 2048 + st * 64 + s0;
  *(bf16x8*)dst = o0;
  *(bf16x8*)(dst + 8) = o1;
}

// ---------------- causal flash attention ----------------
// grid (32 qtiles, 64 bh), 4 waves; wave w owns 16 q-rows. KVBLK=32.
__global__ __launch_bounds__(256) void attn_kernel(const short* __restrict__ qb,
                                                   const short* __restrict__ kb,
                                                   const short* __restrict__ vt,
                                                   short* __restrict__ ob) {
  const float SC = 0.03125f;  // (E^-0.25)^2 = 1/32 folded into scores
  int qt = blockIdx.x, bh = blockIdx.y;
  int b = bh >> 4, h = bh & 15;
  int tid = threadIdx.x;
  int w = tid >> 6, l = tid & 63;
  int l15 = l & 15, lhi = l >> 4;

  __shared__ short p_lds[4][16][32];  // per-wave P tile

  int qrow0 = qt * 64 + w * 16;
  const short* qbase = qb + (size_t)(b * 2048 + qrow0 + l15) * 1024 + h * 64 + lhi * 8;
  bf16x8 aq0 = *(const bf16x8*)(qbase);
  bf16x8 aq1 = *(const bf16x8*)(qbase + 32);

  f32x4 o0 = {0.f, 0.f, 0.f, 0.f}, o1 = o0, o2 = o0, o3 = o0;
  float mrow[4] = {-INFINITY, -INFINITY, -INFINITY, -INFINITY};
  float lrow[4] = {0.f, 0.f, 0.f, 0.f};

  int ntiles = (qt + 1) * 2;
  for (int t = 0; t < ntiles; ++t) {
    int kv0 = t * 32;
    const short* kbase = kb + (size_t)(b * 2048 + kv0 + l15) * 1024 + h * 64 + lhi * 8;
    bf16x8 bk00 = *(const bf16x8*)(kbase);
    bf16x8 bk01 = *(const bf16x8*)(kbase + 32);
    bf16x8 bk10 = *(const bf16x8*)(kbase + 16 * 1024);
    bf16x8 bk11 = *(const bf16x8*)(kbase + 16 * 1024 + 32);
    f32x4 z = {0.f, 0.f, 0.f, 0.f};
    f32x4 sc0 = __builtin_amdgcn_mfma_f32_16x16x32_bf16(aq0, bk00, z, 0, 0, 0);
    sc0 = __builtin_amdgcn_mfma_f32_16x16x32_bf16(aq1, bk01, sc0, 0, 0, 0);
    f32x4 sc1 = __builtin_amdgcn_mfma_f32_16x16x32_bf16(aq0, bk10, z, 0, 0, 0);
    sc1 = __builtin_amdgcn_mfma_f32_16x16x32_bf16(aq1, bk11, sc1, 0, 0, 0);

#pragma unroll
    for (int r = 0; r < 4; ++r) {
      int qg = qrow0 + lhi * 4 + r;
      float s0 = sc0[r] * SC; if (kv0 + l15 > qg) s0 = -INFINITY;
      float s1 = sc1[r] * SC; if (kv0 + 16 + l15 > qg) s1 = -INFINITY;
      float tm = fmaxf(s0, s1);
      tm = fmaxf(tm, __shfl_xor(tm, 1));
      tm = fmaxf(tm, __shfl_xor(tm, 2));
      tm = fmaxf(tm, __shfl_xor(tm, 4));
      tm = fmaxf(tm, __shfl_xor(tm, 8));
      float nm = fmaxf(mrow[r], tm);
      float alpha = __expf(mrow[r] - nm);
      float p0 = __expf(s0 - nm);
      float p1 = __expf(s1 - nm);
      float ps = p0 + p1;
      ps += __shfl_xor(ps, 1);
      ps += __shfl_xor(ps, 2);
      ps += __shfl_xor(ps, 4);
      ps += __shfl_xor(ps, 8);
      lrow[r] = lrow[r] * alpha + ps;
      mrow[r] = nm;
      o0[r] *= alpha; o1[r] *= alpha; o2[r] *= alpha; o3[r] *= alpha;
      p_lds[w][lhi * 4 + r][l15] = f2bf(p0);
      p_lds[w][lhi * 4 + r][16 + l15] = f2bf(p1);
    }
    // P (16x32) as MFMA A-operand: same-wave LDS round-trip, no barrier needed
    bf16x8 pa = *(const bf16x8*)(&p_lds[w][l15][lhi * 8]);
    const short* vbase = vt + (size_t)(bh * 64 + l15) * 2048 + kv0 + lhi * 8;
    bf16x8 bv0 = *(const bf16x8*)(vbase);
    bf16x8 bv1 = *(const bf16x8*)(vbase + 16 * 2048);
    bf16x8 bv2 = *(const bf16x8*)(vbase + 32 * 2048);
    bf16x8 bv3 = *(const bf16x8*)(vbase + 48 * 2048);
    o0 = __builtin_amdgcn_mfma_f32_16x16x32_bf16(pa, bv0, o0, 0, 0, 0);
    o1 = __builtin_amdgcn_mfma_f32_16x16x32_bf16(pa, bv1, o1, 0, 0, 0);
    o2 = __builtin_amdgcn_mfma_f32_16x16x32_bf16(pa, bv2, o2, 0, 0, 0);
    o3 = __builtin_amdgcn_mfma_f32_16x16x32_bf16(pa, bv3, o3, 0, 0, 0);
  }

#pragma unroll
  for (int r = 0; r < 4; ++r) {
    float inv = 1.0f / lrow[r];
    int qg = qrow0 + lhi * 4 + r;
    short* obase = ob + (size_t)(b * 2048 + qg) * 1024 + h * 64 + l15;
    obase[0]  = f2bf(o0[r] * inv);
    obase[16] = f2bf(o1[r] * inv);
    obase[32] = f2bf(o2[r] * inv);
    obase[48] = f2bf(o3[r] * inv);
  }
}

extern "C" void kernel_launch(void* const* d_in, const int* in_sizes, int n_in,
                              void* d_out, int out_size, void* d_ws, size_t ws_size,
                              hipStream_t stream) {
  const float* x  = (const float*)d_in[0];
  const float* Wk = (const float*)d_in[1];
  const float* Wq = (const float*)d_in[2];
  const float* Wv = (const float*)d_in[3];
  const float* Wu = (const float*)d_in[4];
  const float* bu = (const float*)d_in[5];
  float* out = (float*)d_out;

  char* ws = (char*)d_ws;
  const size_t MB = 1u << 20;
  short* xb  = (short*)(ws + 0 * MB);    // 16 MB  x bf16 [8192][1024]
  short* qb  = (short*)(ws + 16 * MB);   // 16 MB
  short* kb  = (short*)(ws + 32 * MB);   // 16 MB
  short* vb  = (short*)(ws + 48 * MB);   // 16 MB
  short* vtb = (short*)(ws + 64 * MB);   // 16 MB  [(b*16+h)*64+d][2048]
  short* ob  = (short*)(ws + 80 * MB);   // 16 MB  attn out bf16
  short* wqb = (short*)(ws + 96 * MB);   // 2 MB
  short* wkb = (short*)(ws + 98 * MB);   // 2 MB
  short* wvb = (short*)(ws + 100 * MB);  // 2 MB
  short* wub = (short*)(ws + 102 * MB);  // 2 MB

  cast_kernel<<<4096, 256, 0, stream>>>(x, xb, 8388608);
  cast_kernel<<<512, 256, 0, stream>>>(Wq, wqb, 1048576);
  cast_kernel<<<512, 256, 0, stream>>>(Wk, wkb, 1048576);
  cast_kernel<<<512, 256, 0, stream>>>(Wv, wvb, 1048576);
  cast_kernel<<<512, 256, 0, stream>>>(Wu, wub, 1048576);

  gemm_qkv_kernel<<<dim3(64, 8, 3), 256, 0, stream>>>(xb, wqb, wkb, wvb, qb, kb, vb);
  transpose_v_kernel<<<dim3(32, 64), 256, 0, stream>>>(vb, vtb);
  attn_kernel<<<dim3(32, 64), 256, 0, stream>>>(qb, kb, vtb, ob);
  gemm_out_kernel<<<dim3(64, 8), 256, 0, stream>>>(ob, wub, bu, out);
}

// Round 2
// 267.741 us; speedup vs baseline: 2.1007x; 2.1007x over previous
//
#include <hip/hip_runtime.h>
#include <stdint.h>
#include <math.h>

// Problem: B=4, S=2048, E=1024, H=16, D=64
// d_in order (setup_inputs dict): x, Wk, Wq, Wv, Wu, bu   (note Wk before Wq!)

typedef __attribute__((ext_vector_type(8))) short bf16x8;
typedef __attribute__((ext_vector_type(4))) float f32x4;
typedef __attribute__((ext_vector_type(16))) float f32x16;
typedef __attribute__((ext_vector_type(4))) int i32x4;
typedef __attribute__((ext_vector_type(4))) short s16x4;

__device__ __forceinline__ short f2bf(float f) {
  union { float f; uint32_t u; } v; v.f = f;
  uint32_t r = v.u + 0x7FFFu + ((v.u >> 16) & 1u);  // RNE
  return (short)(r >> 16);
}
__device__ __forceinline__ float bf2f(short s) {
  union { uint32_t u; float f; } v; v.u = ((uint32_t)(uint16_t)s) << 16;
  return v.f;
}
__device__ __forceinline__ uint32_t pk2(float a, float b) {
  return (uint32_t)(uint16_t)f2bf(a) | ((uint32_t)(uint16_t)f2bf(b) << 16);
}

// exchange across the lane<32 / lane>=32 split:
// out0[l<32]=a[l], out0[l>=32]=b[l-32]; out1[l<32]=a[l+32], out1[l>=32]=b[l]
__device__ __forceinline__ void swap32(uint32_t a, uint32_t b, int hi,
                                       uint32_t& out0, uint32_t& out1) {
#if __has_builtin(__builtin_amdgcn_permlane32_swap)
  typedef __attribute__((ext_vector_type(2))) int i32x2;
  i32x2 r = __builtin_amdgcn_permlane32_swap((int)a, (int)b, false, false);
  out0 = (uint32_t)r.x; out1 = (uint32_t)r.y;
#else
  uint32_t ta = (uint32_t)__shfl_xor((int)a, 32);
  uint32_t tb = (uint32_t)__shfl_xor((int)b, 32);
  out0 = hi ? tb : a;
  out1 = hi ? b : ta;
#endif
}

// ---------------- cast fp32 -> bf16, vectorized (G13) ----------------
__global__ __launch_bounds__(256) void cast_kernel(const float* __restrict__ src,
                                                   short* __restrict__ dst, int n) {
  int i = (blockIdx.x * 256 + threadIdx.x) * 8;
  if (i >= n) return;
  const float4* s = (const float4*)(src + i);
  float4 f0 = s[0], f1 = s[1];
  bf16x8 o;
  o[0] = f2bf(f0.x); o[1] = f2bf(f0.y); o[2] = f2bf(f0.z); o[3] = f2bf(f0.w);
  o[4] = f2bf(f1.x); o[5] = f2bf(f1.y); o[6] = f2bf(f1.z); o[7] = f2bf(f1.w);
  *(bf16x8*)(dst + i) = o;
}

// ---------------- B^T GEMM: C[i,j] = sum_k A[i,k]*B[j,k] ----------------
template <bool F32OUT>
__device__ __forceinline__ void gemm_bt_core(const short* __restrict__ A,
                                             const short* __restrict__ Bm,
                                             short* __restrict__ Cb,
                                             float* __restrict__ Cf,
                                             const float* __restrict__ bias) {
  __shared__ short a_lds[128 * 64];
  __shared__ short b_lds[128 * 64];
  const int tid = threadIdx.x;
  const int w = tid >> 6, l = tid & 63;
  const int l15 = l & 15, lhi = l >> 4;
  const int wr = w >> 1, wc = w & 1;
  const int row0 = blockIdx.x * 128;
  const int col0 = blockIdx.y * 128;

  f32x4 acc[4][4];
#pragma unroll
  for (int m = 0; m < 4; ++m)
#pragma unroll
    for (int n = 0; n < 4; ++n)
      acc[m][n] = (f32x4){0.f, 0.f, 0.f, 0.f};

  for (int kt = 0; kt < 16; ++kt) {
#pragma unroll
    for (int i = 0; i < 4; ++i) {
      int o = i * 4096 + tid * 16;
      int r = o >> 7;
      int cs = o & 127;
      bf16x8 va = *(const bf16x8*)((const char*)A + (size_t)(row0 + r) * 2048 + kt * 128 + cs);
      bf16x8 vb = *(const bf16x8*)((const char*)Bm + (size_t)(col0 + r) * 2048 + kt * 128 + cs);
      int sw = cs ^ ((r & 7) << 4);
      *(bf16x8*)((char*)a_lds + r * 128 + sw) = va;
      *(bf16x8*)((char*)b_lds + r * 128 + sw) = vb;
    }
    __syncthreads();
#pragma unroll
    for (int kk = 0; kk < 2; ++kk) {
      bf16x8 af[4], bg[4];
#pragma unroll
      for (int m = 0; m < 4; ++m) {
        int r = wr * 64 + m * 16 + l15;
        int cb = (kk * 64 + lhi * 16) ^ ((r & 7) << 4);
        af[m] = *(const bf16x8*)((const char*)a_lds + r * 128 + cb);
      }
#pragma unroll
      for (int n = 0; n < 4; ++n) {
        int r = wc * 64 + n * 16 + l15;
        int cb = (kk * 64 + lhi * 16) ^ ((r & 7) << 4);
        bg[n] = *(const bf16x8*)((const char*)b_lds + r * 128 + cb);
      }
#pragma unroll
      for (int m = 0; m < 4; ++m)
#pragma unroll
        for (int n = 0; n < 4; ++n)
          acc[m][n] = __builtin_amdgcn_mfma_f32_16x16x32_bf16(af[m], bg[n], acc[m][n], 0, 0, 0);
    }
    __syncthreads();
  }

#pragma unroll
  for (int m = 0; m < 4; ++m) {
#pragma unroll
    for (int n = 0; n < 4; ++n) {
      int colg = col0 + wc * 64 + n * 16 + l15;
#pragma unroll
      for (int r = 0; r < 4; ++r) {
        int rowg = row0 + wr * 64 + m * 16 + lhi * 4 + r;
        float v = acc[m][n][r];
        if constexpr (F32OUT) {
          Cf[(size_t)rowg * 1024 + colg] = v + bias[colg];
        } else {
          Cb[(size_t)rowg * 1024 + colg] = f2bf(v);
        }
      }
    }
  }
}

__global__ __launch_bounds__(256) void gemm_qkv_kernel(const short* __restrict__ xb,
                                                       const short* __restrict__ wq,
                                                       const short* __restrict__ wk,
                                                       const short* __restrict__ wv,
                                                       short* qo, short* ko, short* vo) {
  const short* Bm = (blockIdx.z == 0) ? wq : (blockIdx.z == 1) ? wk : wv;
  short* C = (blockIdx.z == 0) ? qo : (blockIdx.z == 1) ? ko : vo;
  gemm_bt_core<false>(xb, Bm, C, nullptr, nullptr);
}

__global__ __launch_bounds__(256) void gemm_out_kernel(const short* __restrict__ ob,
                                                       const short* __restrict__ wu,
                                                       const float* __restrict__ bias,
                                                       float* __restrict__ out) {
  gemm_bt_core<true>(ob, wu, nullptr, out, bias);
}

// ---------------- V transpose: v[b,s,h,d] -> vt[(b*16+h)*64+d][s] ----------------
__global__ __launch_bounds__(256) void transpose_v_kernel(const short* __restrict__ vb,
                                                          short* __restrict__ vt) {
  int st = blockIdx.x, bh = blockIdx.y;
  int b = bh >> 4, h = bh & 15;
  __shared__ short tile[64][66];
  int tid = threadIdx.x;
  int sl = tid >> 2;
  int d0 = (tid & 3) * 16;
  const short* src = vb + (size_t)(b * 2048 + st * 64 + sl) * 1024 + h * 64 + d0;
  bf16x8 v0 = *(const bf16x8*)(src);
  bf16x8 v1 = *(const bf16x8*)(src + 8);
#pragma unroll
  for (int i = 0; i < 8; ++i) tile[d0 + i][sl] = v0[i];
#pragma unroll
  for (int i = 0; i < 8; ++i) tile[d0 + 8 + i][sl] = v1[i];
  __syncthreads();
  int d = tid >> 2;
  int s0 = (tid & 3) * 16;
  bf16x8 o0, o1;
#pragma unroll
  for (int i = 0; i < 8; ++i) o0[i] = tile[d][s0 + i];
#pragma unroll
  for (int i = 0; i < 8; ++i) o1[i] = tile[d][s0 + 8 + i];
  short* dst = vt + (size_t)(bh * 64 + d) * 2048 + st * 64 + s0;
  *(bf16x8*)dst = o0;
  *(bf16x8*)(dst + 8) = o1;
}

// ---------------- causal flash attention, swapped-QK^T 32x32 (m214-style) ----
// grid (16, 64), 4 waves. Wave owns 32 q-rows; balanced causal pairing:
// waves 0,1 -> qt*64 + w*32 ; waves 2,3 -> (2048-64-qt*64) + (w-2)*32.
// Lane l owns q-row (l&31); S^T via mfma(K,Q) keeps softmax lane-local.
__global__ __launch_bounds__(256) void attn_kernel(const short* __restrict__ qb,
                                                   const short* __restrict__ kb,
                                                   const short* __restrict__ vt,
                                                   short* __restrict__ ob) {
  int qt = blockIdx.x, bh = blockIdx.y;
  int b = bh >> 4, h = bh & 15;
  int tid = threadIdx.x;
  int w = tid >> 6, l = tid & 63;
  int l31 = l & 31, hi = l >> 5;

  int qrow0 = (w < 2) ? (qt * 64 + w * 32) : (1984 - qt * 64 + (w - 2) * 32);
  int ntiles = (qrow0 >> 5) + 1;

  // Q fragments, pre-scaled by 1/32 = (E^-0.25)^2 (power of 2: exact in bf16)
  const short* qbase = qb + (size_t)(b * 2048 + qrow0 + l31) * 1024 + h * 64 + hi * 8;
  bf16x8 aq[4];
#pragma unroll
  for (int s = 0; s < 4; ++s) {
    bf16x8 t = *(const bf16x8*)(qbase + s * 16);
#pragma unroll
    for (int j = 0; j < 8; ++j) t[j] = f2bf(bf2f(t[j]) * 0.03125f);
    aq[s] = t;
  }

  f32x16 o_lo = {}, o_hi = {};
  float m = -INFINITY, lsum = 0.f;

  const short* kbase0 = kb + (size_t)(b * 2048 + l31) * 1024 + h * 64 + hi * 8;
  const short* vb0 = vt + (size_t)(bh * 64 + l31) * 2048 + hi * 8;
  const short* vb1 = vb0 + 32 * 2048;

  for (int t = 0; t < ntiles; ++t) {
    int kv0 = t * 32;
    // K fragments: lane holds K[k=kv0+l31][d-slice]
    const short* kbase = kbase0 + (size_t)kv0 * 1024;
    f32x16 st = {};
#pragma unroll
    for (int s = 0; s < 4; ++s) {
      bf16x8 ak = *(const bf16x8*)(kbase + s * 16);
      st = __builtin_amdgcn_mfma_f32_32x32x16_bf16(ak, aq[s], st, 0, 0, 0);
    }

    if (kv0 == qrow0) {  // diagonal tile: mask k > q (wave-uniform branch)
#pragma unroll
      for (int r = 0; r < 16; ++r) {
        int crow = (r & 3) + 8 * (r >> 2) + 4 * hi;
        if (crow > l31) st[r] = -INFINITY;
      }
    }

    // lane-local row max (q = l31; partner lane l^32 holds other k-half)
    float pmax = st[0];
#pragma unroll
    for (int r = 1; r < 16; ++r) pmax = fmaxf(pmax, st[r]);
    pmax = fmaxf(pmax, __shfl_xor(pmax, 32));

    // T13 defer-max: only rescale when tile max exceeds running max + 8
    if (pmax > m + 8.f) {
      float alpha = __expf(m - pmax);
      m = pmax;
      lsum *= alpha;
#pragma unroll
      for (int r = 0; r < 16; ++r) { o_lo[r] *= alpha; o_hi[r] *= alpha; }
    }

    float p[16];
    float ts = 0.f;
#pragma unroll
    for (int r = 0; r < 16; ++r) { p[r] = __expf(st[r] - m); ts += p[r]; }
    lsum += ts;

    // T12: P -> bf16 A-fragments via pack + permlane32_swap.
    // own p[r] = P[q=l31][k = (r&3)+8*(r>>2)+4*hi]
    uint32_t a0, a2, b1, b3, c0, c2, d1, d3;
    swap32(pk2(p[0], p[1]),   pk2(p[4], p[5]),   hi, a0, a2);
    swap32(pk2(p[2], p[3]),   pk2(p[6], p[7]),   hi, b1, b3);
    swap32(pk2(p[8], p[9]),   pk2(p[12], p[13]), hi, c0, c2);
    swap32(pk2(p[10], p[11]), pk2(p[14], p[15]), hi, d1, d3);
    i32x4 w0 = {(int)a0, (int)b1, (int)a2, (int)b3};  // P[q][k = hi*8 + j]
    i32x4 w1 = {(int)c0, (int)d1, (int)c2, (int)d3};  // P[q][k = 16 + hi*8 + j]
    bf16x8 pa0 = __builtin_bit_cast(bf16x8, w0);
    bf16x8 pa1 = __builtin_bit_cast(bf16x8, w1);

    // PV: O^T += V^T * P^T  (keeps q on lane axis -> lane-local rescale)
    const short* vk0 = vb0 + kv0;
    const short* vk1 = vb1 + kv0;
    bf16x8 av;
    av = *(const bf16x8*)(vk0);
    o_lo = __builtin_amdgcn_mfma_f32_32x32x16_bf16(av, pa0, o_lo, 0, 0, 0);
    av = *(const bf16x8*)(vk1);
    o_hi = __builtin_amdgcn_mfma_f32_32x32x16_bf16(av, pa0, o_hi, 0, 0, 0);
    av = *(const bf16x8*)(vk0 + 16);
    o_lo = __builtin_amdgcn_mfma_f32_32x32x16_bf16(av, pa1, o_lo, 0, 0, 0);
    av = *(const bf16x8*)(vk1 + 16);
    o_hi = __builtin_amdgcn_mfma_f32_32x32x16_bf16(av, pa1, o_hi, 0, 0, 0);
  }

  lsum += __shfl_xor(lsum, 32);
  float inv = 1.0f / lsum;
  short* obase = ob + (size_t)(b * 2048 + qrow0 + l31) * 1024 + h * 64;
#pragma unroll
  for (int g = 0; g < 4; ++g) {
    int d0 = 8 * g + 4 * hi;
    s16x4 v0, v1;
#pragma unroll
    for (int j = 0; j < 4; ++j) {
      v0[j] = f2bf(o_lo[4 * g + j] * inv);
      v1[j] = f2bf(o_hi[4 * g + j] * inv);
    }
    *(s16x4*)(obase + d0) = v0;
    *(s16x4*)(obase + 32 + d0) = v1;
  }
}

extern "C" void kernel_launch(void* const* d_in, const int* in_sizes, int n_in,
                              void* d_out, int out_size, void* d_ws, size_t ws_size,
                              hipStream_t stream) {
  const float* x  = (const float*)d_in[0];
  const float* Wk = (const float*)d_in[1];
  const float* Wq = (const float*)d_in[2];
  const float* Wv = (const float*)d_in[3];
  const float* Wu = (const float*)d_in[4];
  const float* bu = (const float*)d_in[5];
  float* out = (float*)d_out;

  char* ws = (char*)d_ws;
  const size_t MB = 1u << 20;
  short* xb  = (short*)(ws + 0 * MB);
  short* qb  = (short*)(ws + 16 * MB);
  short* kb  = (short*)(ws + 32 * MB);
  short* vb  = (short*)(ws + 48 * MB);
  short* vtb = (short*)(ws + 64 * MB);
  short* ob  = (short*)(ws + 80 * MB);
  short* wqb = (short*)(ws + 96 * MB);
  short* wkb = (short*)(ws + 98 * MB);
  short* wvb = (short*)(ws + 100 * MB);
  short* wub = (short*)(ws + 102 * MB);

  cast_kernel<<<4096, 256, 0, stream>>>(x, xb, 8388608);
  cast_kernel<<<512, 256, 0, stream>>>(Wq, wqb, 1048576);
  cast_kernel<<<512, 256, 0, stream>>>(Wk, wkb, 1048576);
  cast_kernel<<<512, 256, 0, stream>>>(Wv, wvb, 1048576);
  cast_kernel<<<512, 256, 0, stream>>>(Wu, wub, 1048576);

  gemm_qkv_kernel<<<dim3(64, 8, 3), 256, 0, stream>>>(xb, wqb, wkb, wvb, qb, kb, vb);
  transpose_v_kernel<<<dim3(32, 64), 256, 0, stream>>>(vb, vtb);
  attn_kernel<<<dim3(16, 64), 256, 0, stream>>>(qb, kb, vtb, ob);
  gemm_out_kernel<<<dim3(64, 8), 256, 0, stream>>>(ob, wub, bu, out);
}

// Round 3
// 246.208 us; speedup vs baseline: 2.2844x; 1.0875x over previous
//
#include <hip/hip_runtime.h>
#include <stdint.h>
#include <math.h>

// Problem: B=4, S=2048, E=1024, H=16, D=64
// d_in order (setup_inputs dict): x, Wk, Wq, Wv, Wu, bu   (note Wk before Wq!)

typedef __attribute__((ext_vector_type(8))) short bf16x8;
typedef __attribute__((ext_vector_type(4))) float f32x4;
typedef __attribute__((ext_vector_type(16))) float f32x16;
typedef __attribute__((ext_vector_type(4))) int i32x4;
typedef __attribute__((ext_vector_type(4))) short s16x4;

#define GLOAD_LDS16(gp, lp)                                                     \
  __builtin_amdgcn_global_load_lds(                                             \
      (__attribute__((address_space(1))) void*)(gp),                            \
      (__attribute__((address_space(3))) void*)(lp), 16, 0, 0)

__device__ __forceinline__ short f2bf(float f) {
  union { float f; uint32_t u; } v; v.f = f;
  uint32_t r = v.u + 0x7FFFu + ((v.u >> 16) & 1u);  // RNE
  return (short)(r >> 16);
}
__device__ __forceinline__ float bf2f(short s) {
  union { uint32_t u; float f; } v; v.u = ((uint32_t)(uint16_t)s) << 16;
  return v.f;
}
// native converts (compiler pairs into v_cvt_pk_bf16_f32)
__device__ __forceinline__ short f2bfn(float f) {
  union { __bf16 h; short s; } u; u.h = (__bf16)f; return u.s;
}
__device__ __forceinline__ uint32_t pk2n(float a, float b) {
  union { __bf16 h[2]; uint32_t u; } v;
  v.h[0] = (__bf16)a; v.h[1] = (__bf16)b;
  return v.u;
}

// exchange across the lane<32 / lane>=32 split (T12)
__device__ __forceinline__ void swap32(uint32_t a, uint32_t b, int hi,
                                       uint32_t& out0, uint32_t& out1) {
#if __has_builtin(__builtin_amdgcn_permlane32_swap)
  typedef __attribute__((ext_vector_type(2))) int i32x2;
  i32x2 r = __builtin_amdgcn_permlane32_swap((int)a, (int)b, false, false);
  out0 = (uint32_t)r.x; out1 = (uint32_t)r.y;
#else
  uint32_t ta = (uint32_t)__shfl_xor((int)a, 32);
  uint32_t tb = (uint32_t)__shfl_xor((int)b, 32);
  out0 = hi ? tb : a;
  out1 = hi ? b : ta;
#endif
}

// ---------------- cast fp32 -> bf16, vectorized (G13) ----------------
__global__ __launch_bounds__(256) void cast_kernel(const float* __restrict__ src,
                                                   short* __restrict__ dst, int n) {
  int i = (blockIdx.x * 256 + threadIdx.x) * 8;
  if (i >= n) return;
  const float4* s = (const float4*)(src + i);
  float4 f0 = s[0], f1 = s[1];
  bf16x8 o;
  o[0] = f2bf(f0.x); o[1] = f2bf(f0.y); o[2] = f2bf(f0.z); o[3] = f2bf(f0.w);
  o[4] = f2bf(f1.x); o[5] = f2bf(f1.y); o[6] = f2bf(f1.z); o[7] = f2bf(f1.w);
  *(bf16x8*)(dst + i) = o;
}

__global__ __launch_bounds__(256) void cast4_kernel(const float* __restrict__ w0,
                                                    const float* __restrict__ w1,
                                                    const float* __restrict__ w2,
                                                    const float* __restrict__ w3,
                                                    short* o0, short* o1, short* o2, short* o3) {
  const float* src = (blockIdx.y == 0) ? w0 : (blockIdx.y == 1) ? w1 : (blockIdx.y == 2) ? w2 : w3;
  short* dst = (blockIdx.y == 0) ? o0 : (blockIdx.y == 1) ? o1 : (blockIdx.y == 2) ? o2 : o3;
  int i = (blockIdx.x * 256 + threadIdx.x) * 8;
  const float4* s = (const float4*)(src + i);
  float4 f0 = s[0], f1 = s[1];
  bf16x8 o;
  o[0] = f2bf(f0.x); o[1] = f2bf(f0.y); o[2] = f2bf(f0.z); o[3] = f2bf(f0.w);
  o[4] = f2bf(f1.x); o[5] = f2bf(f1.y); o[6] = f2bf(f1.z); o[7] = f2bf(f1.w);
  *(bf16x8*)(dst + i) = o;
}

// ---------------- B^T GEMM (m97 structure): C[i,j] = sum_k A[i,k]*B[j,k] ----
// 128x128 tile, 4 waves (2x2), BK=64, global_load_lds width-16, linear LDS.
template <bool F32OUT>
__device__ __forceinline__ void gemm_bt_core(const short* __restrict__ A,
                                             const short* __restrict__ Bm,
                                             short* __restrict__ Cb,
                                             float* __restrict__ Cf,
                                             const float* __restrict__ bias) {
  __shared__ short a_lds[128 * 64];
  __shared__ short b_lds[128 * 64];
  const int tid = threadIdx.x;
  const int w = tid >> 6, l = tid & 63;
  const int l15 = l & 15, lhi = l >> 4;
  const int wr = w >> 1, wc = w & 1;
  const int row0 = blockIdx.x * 128;
  const int col0 = blockIdx.y * 128;

  f32x4 acc[4][4];
#pragma unroll
  for (int m = 0; m < 4; ++m)
#pragma unroll
    for (int n = 0; n < 4; ++n)
      acc[m][n] = (f32x4){0.f, 0.f, 0.f, 0.f};

  // per-thread staging slot: linear byte offset o = i*4096 + tid*16
  const int o0 = tid * 16;
  const int sr = o0 >> 7;        // row within 32-row group
  const int sc = o0 & 127;       // byte col

  for (int kt = 0; kt < 16; ++kt) {
    const char* Ab = (const char*)A + (size_t)(row0 + sr) * 2048 + kt * 128 + sc;
    const char* Bb = (const char*)Bm + (size_t)(col0 + sr) * 2048 + kt * 128 + sc;
#pragma unroll
    for (int i = 0; i < 4; ++i) {
      GLOAD_LDS16(Ab + (size_t)i * 32 * 2048, (char*)a_lds + i * 4096 + o0);
      GLOAD_LDS16(Bb + (size_t)i * 32 * 2048, (char*)b_lds + i * 4096 + o0);
    }
    __syncthreads();
#pragma unroll
    for (int kk = 0; kk < 2; ++kk) {
      bf16x8 af[4], bg[4];
#pragma unroll
      for (int m = 0; m < 4; ++m) {
        int r = wr * 64 + m * 16 + l15;
        af[m] = *(const bf16x8*)((const char*)a_lds + r * 128 + kk * 64 + lhi * 16);
      }
#pragma unroll
      for (int n = 0; n < 4; ++n) {
        int r = wc * 64 + n * 16 + l15;
        bg[n] = *(const bf16x8*)((const char*)b_lds + r * 128 + kk * 64 + lhi * 16);
      }
#pragma unroll
      for (int m = 0; m < 4; ++m)
#pragma unroll
        for (int n = 0; n < 4; ++n)
          acc[m][n] = __builtin_amdgcn_mfma_f32_16x16x32_bf16(af[m], bg[n], acc[m][n], 0, 0, 0);
    }
    __syncthreads();
  }

#pragma unroll
  for (int m = 0; m < 4; ++m) {
#pragma unroll
    for (int n = 0; n < 4; ++n) {
      int colg = col0 + wc * 64 + n * 16 + l15;
#pragma unroll
      for (int r = 0; r < 4; ++r) {
        int rowg = row0 + wr * 64 + m * 16 + lhi * 4 + r;
        float v = acc[m][n][r];
        if constexpr (F32OUT) {
          Cf[(size_t)rowg * 1024 + colg] = v + bias[colg];
        } else {
          Cb[(size_t)rowg * 1024 + colg] = f2bfn(v);
        }
      }
    }
  }
}

__global__ __launch_bounds__(256) void gemm_qkv_kernel(const short* __restrict__ xb,
                                                       const short* __restrict__ wq,
                                                       const short* __restrict__ wk,
                                                       const short* __restrict__ wv,
                                                       short* qo, short* ko, short* vo) {
  const short* Bm = (blockIdx.z == 0) ? wq : (blockIdx.z == 1) ? wk : wv;
  short* C = (blockIdx.z == 0) ? qo : (blockIdx.z == 1) ? ko : vo;
  gemm_bt_core<false>(xb, Bm, C, nullptr, nullptr);
}

__global__ __launch_bounds__(256) void gemm_out_kernel(const short* __restrict__ ob,
                                                       const short* __restrict__ wu,
                                                       const float* __restrict__ bias,
                                                       float* __restrict__ out) {
  gemm_bt_core<true>(ob, wu, nullptr, out, bias);
}

// ---------------- V transpose: v[b,s,h,d] -> vt[(b*16+h)*64+d][s] ----------------
__global__ __launch_bounds__(256) void transpose_v_kernel(const short* __restrict__ vb,
                                                          short* __restrict__ vt) {
  int st = blockIdx.x, bh = blockIdx.y;
  int b = bh >> 4, h = bh & 15;
  __shared__ short tile[64][66];
  int tid = threadIdx.x;
  int sl = tid >> 2;
  int d0 = (tid & 3) * 16;
  const short* src = vb + (size_t)(b * 2048 + st * 64 + sl) * 1024 + h * 64 + d0;
  bf16x8 v0 = *(const bf16x8*)(src);
  bf16x8 v1 = *(const bf16x8*)(src + 8);
#pragma unroll
  for (int i = 0; i < 8; ++i) tile[d0 + i][sl] = v0[i];
#pragma unroll
  for (int i = 0; i < 8; ++i) tile[d0 + 8 + i][sl] = v1[i];
  __syncthreads();
  int d = tid >> 2;
  int s0 = (tid & 3) * 16;
  bf16x8 o0, o1;
#pragma unroll
  for (int i = 0; i < 8; ++i) o0[i] = tile[d][s0 + i];
#pragma unroll
  for (int i = 0; i < 8; ++i) o1[i] = tile[d][s0 + 8 + i];
  short* dst = vt + (size_t)(bh * 64 + d) * 2048 + st * 64 + s0;
  *(bf16x8*)dst = o0;
  *(bf16x8*)(dst + 8) = o1;
}

// ---------------- causal flash attention v3 ----------------
// 2048 equal-work waves: wave = pair (strip i, strip 63-i), ~33 dual(64k)-iters.
// grid (8, 64) x 256 thr. Lane l owns q-row (l&31); swapped QK^T (mfma(K,Q)).
// log2-domain softmax: Q pre-scaled by E^-0.5 * log2(e); exp2f = bare v_exp_f32.
__global__ __launch_bounds__(256) void attn_kernel(const short* __restrict__ qb,
                                                   const short* __restrict__ kb,
                                                   const short* __restrict__ vt,
                                                   short* __restrict__ ob) {
  const float QSCALE = 0.03125f * 1.44269504f;  // (E^-0.25)^2 * log2(e)
  const float THR = 11.5416f;                   // 8 * log2(e)
  int pg = blockIdx.x, bh = blockIdx.y;
  int b = bh >> 4, h = bh & 15;
  int w = threadIdx.x >> 6, l = threadIdx.x & 63;
  int l31 = l & 31, hi = l >> 5;
  int i = pg * 4 + w;  // pair index 0..31

  const short* kstrip = kb + ((size_t)b * 2048 + l31) * 1024 + h * 64 + hi * 8;
  const short* vlo = vt + ((size_t)bh * 64 + l31) * 2048 + hi * 8;
  const short* vhi = vlo + 32 * 2048;

#pragma unroll
  for (int part = 0; part < 2; ++part) {
    int strip = part ? (63 - i) : i;
    int qrow0 = strip * 32;
    const short* qbase = qb + ((size_t)(b * 2048 + qrow0 + l31)) * 1024 + h * 64 + hi * 8;
    bf16x8 aq[4];
#pragma unroll
    for (int s = 0; s < 4; ++s) {
      bf16x8 t = *(const bf16x8*)(qbase + s * 16);
#pragma unroll
      for (int j = 0; j < 8; ++j) t[j] = f2bfn(bf2f(t[j]) * QSCALE);
      aq[s] = t;
    }

    f32x16 o_lo = {}, o_hi = {};
    float mr = -INFINITY, lsum = 0.f;
    int nd = (strip + 2) >> 1;  // dual-tile iterations

    bf16x8 kc[8];
#pragma unroll
    for (int s = 0; s < 4; ++s) {
      kc[s]     = *(const bf16x8*)(kstrip + s * 16);
      kc[4 + s] = *(const bf16x8*)(kstrip + (size_t)32 * 1024 + s * 16);
    }

    for (int t = 0; t < nd; ++t) {
      int k0 = t * 64;
      f32x16 st0 = {}, st1 = {};
#pragma unroll
      for (int s = 0; s < 4; ++s)
        st0 = __builtin_amdgcn_mfma_f32_32x32x16_bf16(kc[s], aq[s], st0, 0, 0, 0);
#pragma unroll
      for (int s = 0; s < 4; ++s)
        st1 = __builtin_amdgcn_mfma_f32_32x32x16_bf16(kc[4 + s], aq[s], st1, 0, 0, 0);

      // prefetch next K (clamped address keeps it in-bounds; values unused on last iter)
      int kp = (t + 1 < nd) ? (k0 + 64) : 0;
      bf16x8 kn[8];
#pragma unroll
      for (int s = 0; s < 4; ++s) {
        kn[s]     = *(const bf16x8*)(kstrip + (size_t)kp * 1024 + s * 16);
        kn[4 + s] = *(const bf16x8*)(kstrip + (size_t)(kp + 32) * 1024 + s * 16);
      }
      // V loads issued before softmax; consumed after
      bf16x8 vc[8];
#pragma unroll
      for (int ks = 0; ks < 4; ++ks) {
        vc[ks]     = *(const bf16x8*)(vlo + k0 + ks * 16);
        vc[4 + ks] = *(const bf16x8*)(vhi + k0 + ks * 16);
      }

      if (k0 + 31 > qrow0) {
#pragma unroll
        for (int r = 0; r < 16; ++r) {
          int kk = k0 + (r & 3) + 8 * (r >> 2) + 4 * hi;
          if (kk > qrow0 + l31) st0[r] = -INFINITY;
        }
      }
      if (k0 + 63 > qrow0) {
#pragma unroll
        for (int r = 0; r < 16; ++r) {
          int kk = k0 + 32 + (r & 3) + 8 * (r >> 2) + 4 * hi;
          if (kk > qrow0 + l31) st1[r] = -INFINITY;
        }
      }

      float pmax = fmaxf(st0[0], st1[0]);
#pragma unroll
      for (int r = 1; r < 16; ++r) pmax = fmaxf(pmax, fmaxf(st0[r], st1[r]));
      pmax = fmaxf(pmax, __shfl_xor(pmax, 32));

      if (pmax > mr + THR) {  // T13 defer-max
        float alpha = exp2f(mr - pmax);
        mr = pmax;
        lsum *= alpha;
#pragma unroll
        for (int r = 0; r < 16; ++r) { o_lo[r] *= alpha; o_hi[r] *= alpha; }
      }

      float ts = 0.f;
#pragma unroll
      for (int r = 0; r < 16; ++r) { st0[r] = exp2f(st0[r] - mr); ts += st0[r]; }
#pragma unroll
      for (int r = 0; r < 16; ++r) { st1[r] = exp2f(st1[r] - mr); ts += st1[r]; }
      lsum += ts;

      // T12 pack: P -> bf16 A-fragments
      uint32_t a0, a2, b1, b3, c0, c2, d1, d3;
      swap32(pk2n(st0[0], st0[1]),   pk2n(st0[4], st0[5]),   hi, a0, a2);
      swap32(pk2n(st0[2], st0[3]),   pk2n(st0[6], st0[7]),   hi, b1, b3);
      swap32(pk2n(st0[8], st0[9]),   pk2n(st0[12], st0[13]), hi, c0, c2);
      swap32(pk2n(st0[10], st0[11]), pk2n(st0[14], st0[15]), hi, d1, d3);
      i32x4 w0 = {(int)a0, (int)b1, (int)a2, (int)b3};
      i32x4 w1 = {(int)c0, (int)d1, (int)c2, (int)d3};
      swap32(pk2n(st1[0], st1[1]),   pk2n(st1[4], st1[5]),   hi, a0, a2);
      swap32(pk2n(st1[2], st1[3]),   pk2n(st1[6], st1[7]),   hi, b1, b3);
      swap32(pk2n(st1[8], st1[9]),   pk2n(st1[12], st1[13]), hi, c0, c2);
      swap32(pk2n(st1[10], st1[11]), pk2n(st1[14], st1[15]), hi, d1, d3);
      i32x4 w2 = {(int)a0, (int)b1, (int)a2, (int)b3};
      i32x4 w3 = {(int)c0, (int)d1, (int)c2, (int)d3};
      bf16x8 pa0 = __builtin_bit_cast(bf16x8, w0);
      bf16x8 pa1 = __builtin_bit_cast(bf16x8, w1);
      bf16x8 pa2 = __builtin_bit_cast(bf16x8, w2);
      bf16x8 pa3 = __builtin_bit_cast(bf16x8, w3);

      o_lo = __builtin_amdgcn_mfma_f32_32x32x16_bf16(vc[0], pa0, o_lo, 0, 0, 0);
      o_hi = __builtin_amdgcn_mfma_f32_32x32x16_bf16(vc[4], pa0, o_hi, 0, 0, 0);
      o_lo = __builtin_amdgcn_mfma_f32_32x32x16_bf16(vc[1], pa1, o_lo, 0, 0, 0);
      o_hi = __builtin_amdgcn_mfma_f32_32x32x16_bf16(vc[5], pa1, o_hi, 0, 0, 0);
      o_lo = __builtin_amdgcn_mfma_f32_32x32x16_bf16(vc[2], pa2, o_lo, 0, 0, 0);
      o_hi = __builtin_amdgcn_mfma_f32_32x32x16_bf16(vc[6], pa2, o_hi, 0, 0, 0);
      o_lo = __builtin_amdgcn_mfma_f32_32x32x16_bf16(vc[3], pa3, o_lo, 0, 0, 0);
      o_hi = __builtin_amdgcn_mfma_f32_32x32x16_bf16(vc[7], pa3, o_hi, 0, 0, 0);

#pragma unroll
      for (int s = 0; s < 8; ++s) kc[s] = kn[s];
    }

    lsum += __shfl_xor(lsum, 32);
    float inv = 1.0f / lsum;
    short* obase = ob + (size_t)(b * 2048 + qrow0 + l31) * 1024 + h * 64;
#pragma unroll
    for (int g = 0; g < 4; ++g) {
      int d0 = 8 * g + 4 * hi;
      s16x4 v0, v1;
#pragma unroll
      for (int j = 0; j < 4; ++j) {
        v0[j] = f2bfn(o_lo[4 * g + j] * inv);
        v1[j] = f2bfn(o_hi[4 * g + j] * inv);
      }
      *(s16x4*)(obase + d0) = v0;
      *(s16x4*)(obase + 32 + d0) = v1;
    }
  }
}

extern "C" void kernel_launch(void* const* d_in, const int* in_sizes, int n_in,
                              void* d_out, int out_size, void* d_ws, size_t ws_size,
                              hipStream_t stream) {
  const float* x  = (const float*)d_in[0];
  const float* Wk = (const float*)d_in[1];
  const float* Wq = (const float*)d_in[2];
  const float* Wv = (const float*)d_in[3];
  const float* Wu = (const float*)d_in[4];
  const float* bu = (const float*)d_in[5];
  float* out = (float*)d_out;

  char* ws = (char*)d_ws;
  const size_t MB = 1u << 20;
  short* xb  = (short*)(ws + 0 * MB);
  short* qb  = (short*)(ws + 16 * MB);
  short* kb  = (short*)(ws + 32 * MB);
  short* vb  = (short*)(ws + 48 * MB);
  short* vtb = (short*)(ws + 64 * MB);
  short* ob  = (short*)(ws + 80 * MB);
  short* wqb = (short*)(ws + 96 * MB);
  short* wkb = (short*)(ws + 98 * MB);
  short* wvb = (short*)(ws + 100 * MB);
  short* wub = (short*)(ws + 102 * MB);

  cast_kernel<<<4096, 256, 0, stream>>>(x, xb, 8388608);
  cast4_kernel<<<dim3(512, 4), 256, 0, stream>>>(Wq, Wk, Wv, Wu, wqb, wkb, wvb, wub);

  gemm_qkv_kernel<<<dim3(64, 8, 3), 256, 0, stream>>>(xb, wqb, wkb, wvb, qb, kb, vb);
  transpose_v_kernel<<<dim3(32, 64), 256, 0, stream>>>(vb, vtb);
  attn_kernel<<<dim3(8, 64), 256, 0, stream>>>(qb, kb, vtb, ob);
  gemm_out_kernel<<<dim3(64, 8), 256, 0, stream>>>(ob, wub, bu, out);
}